// Round 9
// baseline (185.534 us; speedup 1.0000x reference)
//
#include <hip/hip_runtime.h>
#include <hip/hip_bf16.h>

// MaskedAttention: out = softmax(tril(q k^T)) v, q/k/v = x @ W{q,k,v}
// B=8 T=2048 D=1024 H=64, fp32 in/out, no 1/sqrt(H) scaling.
//
// Precision plan: q,k projections and QK^T use hi/lo bf16 splitting
// (3-MFMA "bf16x3") so logits are ~fp32-accurate; V/P plain bf16.

typedef __bf16 bf16x8 __attribute__((ext_vector_type(8)));
typedef float f32x4 __attribute__((ext_vector_type(4)));

#define MFMA16(a, b, c) __builtin_amdgcn_mfma_f32_16x16x32_bf16((a), (b), (c), 0, 0, 0)
#define SB0() __builtin_amdgcn_sched_barrier(0)

static constexpr int BB = 8;
static constexpr int TT = 2048;
static constexpr int DD = 1024;
static constexpr int HH = 64;
static constexpr int NROW = BB * TT;       // 16384
// WC slab: [4 colgroups][2 K-halves][320 rows = k8l*5+frag][16 cols][8 bf16]
// frag: 0=q_hi 1=q_lo 2=k_hi 3=k_lo 4=v_hi. 80KB per (cg,half) slice.
static constexpr int WSLICE = 320 * 128;   // bf16 elems per (cg,half) = 80KB

// pack two floats to one u32 of 2 bf16 (lo, hi)
__device__ __forceinline__ unsigned pk2(float a, float b) {
  union { __bf16 h[2]; unsigned u; } r;
  r.h[0] = (__bf16)a;
  r.h[1] = (__bf16)b;
  return r.u;
}

// ---------------------------------------------------------------- W prep ---
// W [1024][64] fp32 -> WC slab (see above). Linear in (row,col) so proj can
// stage it to LDS with pure linear global_load_lds DMA.
__global__ __launch_bounds__(256) void wprep_kernel(
    const float* __restrict__ Wq, const float* __restrict__ Wk,
    const float* __restrict__ Wv, __bf16* __restrict__ WC) {
  int tid = blockIdx.x * 256 + threadIdx.x;
  if (tid >= 64 * 128) return;
  int col = tid >> 7;
  int k8 = tid & 127;
  const int g = col >> 4, c = col & 15;
  const int h2 = k8 >> 6, k8l = k8 & 63;
  bf16x8 q_h, q_l, k_h, k_l, v_h;
#pragma unroll
  for (int j = 0; j < 8; ++j) {
    const int k = k8 * 8 + j;
    float qv = Wq[k * 64 + col];
    float kv = Wk[k * 64 + col];
    float vv = Wv[k * 64 + col];
    __bf16 qhi = (__bf16)qv;
    __bf16 khi = (__bf16)kv;
    q_h[j] = qhi;
    q_l[j] = (__bf16)(qv - (float)qhi);
    k_h[j] = khi;
    k_l[j] = (__bf16)(kv - (float)khi);
    v_h[j] = (__bf16)vv;
  }
  __bf16* base = WC + (size_t)(g * 2 + h2) * WSLICE + (size_t)(k8l * 5) * 128 + c * 8;
  *(bf16x8*)(base) = q_h;            // row k8l*5+0
  *(bf16x8*)(base + 128) = q_l;      // row k8l*5+1
  *(bf16x8*)(base + 256) = k_h;      // row k8l*5+2
  *(bf16x8*)(base + 384) = k_l;      // row k8l*5+3
  *(bf16x8*)(base + 512) = v_h;      // row k8l*5+4
}

// ------------------------------------------------------------ projection ---
// Block = 512 threads (8 waves): 128 rows x ONE 16-col group, K in 2 halves.
// Per half: stage the 80KB W slice into LDS (10x global_load_lds dwordx4
// per thread, one barrier) -- all 8 waves share it (W L2 traffic /8, and
// the DMA engine eats the global latency that killed R2-R4's reg staging).
// Main loop: per 32-K step, 2 x-loads (depth-4 rotation + SB0), 5 conflict-
// free ds_read_b128 (frag read = 4 dense 256B rows), 7 MFMA.
// Grid 512: rg=bid&127, cg=bid>>7 -> same-x blocks share an XCD L2.
__global__ __launch_bounds__(512, 4) void proj_kernel(
    const float* __restrict__ x, const __bf16* __restrict__ WC,
    __bf16* __restrict__ qh, __bf16* __restrict__ ql,
    __bf16* __restrict__ kh, __bf16* __restrict__ kl,
    __bf16* __restrict__ vt) {
  __shared__ __bf16 Wlds[WSLICE];  // 80 KB
  const int tid = threadIdx.x;
  const int w = tid >> 6, l = tid & 63;
  const int lr = l & 15, lg = l >> 4;
  const int rg = blockIdx.x & 127, cg = blockIdx.x >> 7;
  const int r0 = rg * 128 + w * 16;

  const float* xp = x + (size_t)(r0 + lr) * DD + lg * 8;
  // per-frag LDS base (bf16 elems): row (5*lg+m), chunk lr
  const int wb0 = (5 * lg + 0) * 128 + lr * 8;

  f32x4 aq = {0.f, 0.f, 0.f, 0.f};
  f32x4 ak = {0.f, 0.f, 0.f, 0.f};
  f32x4 av = {0.f, 0.f, 0.f, 0.f};
  float4 xa[4], xb[4];

#define LDX(J, OFF)                               \
  do {                                            \
    xa[J] = *(const float4*)(xp + (OFF));         \
    xb[J] = *(const float4*)(xp + (OFF) + 4);     \
  } while (0)

#define CMPW(J, S)                                                    \
  do {                                                                \
    const __bf16* fp = &Wlds[(S) * 2560 + wb0];                       \
    bf16x8 f0 = *(const bf16x8*)(fp);                                 \
    bf16x8 f1 = *(const bf16x8*)(fp + 128);                           \
    bf16x8 f2 = *(const bf16x8*)(fp + 256);                           \
    bf16x8 f3 = *(const bf16x8*)(fp + 384);                           \
    bf16x8 f4 = *(const bf16x8*)(fp + 512);                           \
    float xs[8] = {xa[J].x, xa[J].y, xa[J].z, xa[J].w,                \
                   xb[J].x, xb[J].y, xb[J].z, xb[J].w};               \
    bf16x8 ah, al;                                                    \
    _Pragma("unroll") for (int j = 0; j < 8; ++j) {                   \
      __bf16 hv = (__bf16)xs[j];                                      \
      ah[j] = hv;                                                     \
      al[j] = (__bf16)(xs[j] - (float)hv);                            \
    }                                                                 \
    aq = MFMA16(ah, f0, aq);                                          \
    aq = MFMA16(ah, f1, aq);                                          \
    aq = MFMA16(al, f0, aq);                                          \
    ak = MFMA16(ah, f2, ak);                                          \
    ak = MFMA16(ah, f3, ak);                                          \
    ak = MFMA16(al, f2, ak);                                          \
    av = MFMA16(ah, f4, av);                                          \
  } while (0)

#pragma unroll 1
  for (int h = 0; h < 2; ++h) {
    if (h) __syncthreads();  // all waves done reading half-0 W
    {
      const __bf16* wsrc = WC + (size_t)(cg * 2 + h) * WSLICE;
      const __bf16* gp = wsrc + (size_t)tid * 8;  // per-lane 16B cell
#pragma unroll
      for (int i2 = 0; i2 < 10; ++i2) {
        __builtin_amdgcn_global_load_lds(
            (const __attribute__((address_space(1))) unsigned int*)(gp + i2 * 4096),
            (__attribute__((address_space(3))) unsigned int*)
                ((char*)Wlds + w * 1024 + i2 * 8192),
            16, 0, 0);
      }
    }
    __syncthreads();  // compiler drains vmcnt before barrier: DMA complete

    const int xoff = h * 512;
    LDX(0, xoff); LDX(1, xoff + 32); LDX(2, xoff + 64); LDX(3, xoff + 96);
    SB0();
#pragma unroll
    for (int s = 0; s < 16; ++s) {
      CMPW(s & 3, s);
      if (s < 12) LDX(s & 3, xoff + (s + 4) * 32);
      SB0();
    }
  }
#undef LDX
#undef CMPW

#pragma unroll
  for (int i = 0; i < 4; ++i) {
    const int row = r0 + lg * 4 + i;  // C-layout: row=(lane>>4)*4+reg
    const int col = cg * 16 + lr;     //           col=lane&15
    const size_t oq = (size_t)row * 64 + col;
    float qv = aq[i];
    __bf16 qhi = (__bf16)qv;
    qh[oq] = qhi;
    ql[oq] = (__bf16)(qv - (float)qhi);
    float kv = ak[i];
    __bf16 khi = (__bf16)kv;
    kh[oq] = khi;
    kl[oq] = (__bf16)(kv - (float)khi);
    const int bb = row >> 11, tt = row & 2047;
    vt[((size_t)bb * 64 + col) * 2048 + tt] = (__bf16)av[i];
  }
}

// -------------------------------------------------------------- attention ---
// Split-K flash, 8-WAY with in-register softmax. R8 post-mortem: 4-wave
// blocks = 4 waves/SIMD (Occ 28%) could not hide the per-iter chain
// (2-3 vmcnt waits + MFMA + DS latency); softmax rewrite alone bought 3us.
// This round: 8 waves/block, kt stride 8, two-stage OB4 merge (18.5KB LDS),
// __launch_bounds__(512,8) = 64-VGPR cap -- safe NOW because the in-reg-
// softmax loop measured 56 VGPRs (R7's spill was the old 100-VGPR loop).
// Invariants held: 1024 blocks all resident (4/CU), b=bid&7 XCD affinity.
__global__ __launch_bounds__(512, 8) void attn_kernel(
    const __bf16* __restrict__ qh, const __bf16* __restrict__ ql,
    const __bf16* __restrict__ kh, const __bf16* __restrict__ kl,
    const __bf16* __restrict__ vt, float* __restrict__ out) {
  __shared__ float Sm[8][16];       // per-wave row maxes
  __shared__ float Sl[8][16];       // per-wave row sums
  __shared__ float OB4[4][16][68];  // two-stage merge buffer (68 pad: <=2-way)
  __shared__ float Dinv[16];        // 1/denom per row
  const int w = threadIdx.x >> 6, l = threadIdx.x & 63;
  const int lr = l & 15, lg = l >> 4;
  const int b = blockIdx.x & 7;            // XCD affinity: batch -> XCD
  const int qt = 127 - (blockIdx.x >> 3);  // heavy tiles first
  const int q0 = qt * 16;
  const float NEG = -__builtin_inff();

  // Q fragments (B-operand of the swapped QK^T)
  const size_t qb = ((size_t)b * TT + q0 + lr) * 64 + lg * 8;
  const bf16x8 fqh0 = *(const bf16x8*)(qh + qb);
  const bf16x8 fqh1 = *(const bf16x8*)(qh + qb + 32);
  const bf16x8 fql0 = *(const bf16x8*)(ql + qb);
  const bf16x8 fql1 = *(const bf16x8*)(ql + qb + 32);

  f32x4 o0 = {0.f, 0.f, 0.f, 0.f}, o1 = o0, o2 = o0, o3 = o0;
  float m_s = NEG;   // running max for q-row (q0+lr), shared by 4 lg-lanes
  float su_s = 0.f;  // partial denom for q-row (this lane's keys only)
  const int nkt = (q0 + 47) >> 5;  // ceil((q0+16)/32)

#pragma unroll 1
  for (int kt = w; kt < nkt; kt += 8) {
    const int j0 = kt * 32;
    const f32x4 z = {0.f, 0.f, 0.f, 0.f};
    // ---- all loads up front (KB unconditional: in-bounds, masked later) ----
    const size_t kbA = ((size_t)b * TT + j0 + lr) * 64 + lg * 8;
    const size_t kbB = kbA + (size_t)16 * 64;
    const size_t vb = ((size_t)b * 64 + lr) * 2048 + j0 + lg * 8;
    const bf16x8 fk0 = *(const bf16x8*)(kh + kbA);
    const bf16x8 fk1 = *(const bf16x8*)(kh + kbA + 32);
    const bf16x8 fl0 = *(const bf16x8*)(kl + kbA);
    const bf16x8 fl1 = *(const bf16x8*)(kl + kbA + 32);
    const bf16x8 gk0 = *(const bf16x8*)(kh + kbB);
    const bf16x8 gk1 = *(const bf16x8*)(kh + kbB + 32);
    const bf16x8 gl0 = *(const bf16x8*)(kl + kbB);
    const bf16x8 gl1 = *(const bf16x8*)(kl + kbB + 32);
    const bf16x8 v0 = *(const bf16x8*)(vt + vb);
    const bf16x8 v1 = *(const bf16x8*)(vt + vb + (size_t)16 * 2048);
    const bf16x8 v2 = *(const bf16x8*)(vt + vb + (size_t)32 * 2048);
    const bf16x8 v3 = *(const bf16x8*)(vt + vb + (size_t)48 * 2048);
    SB0();  // loads may not sink past this point

    // swapped QK^T: S^T[key][q].  sa: keys j0+lg*4+i, q=q0+lr.
    f32x4 sa, sb = {NEG, NEG, NEG, NEG};
    {
      f32x4 c0 = MFMA16(fk1, fqh1, MFMA16(fk0, fqh0, z));
      f32x4 c1 = MFMA16(fk1, fql1, MFMA16(fk0, fql0, z));
      f32x4 c2 = MFMA16(fl1, fqh1, MFMA16(fl0, fqh0, z));
      sa = c0 + c1 + c2;
    }
    const bool haveB = (j0 + 16) <= (q0 + 15);
    if (haveB) {
      f32x4 c0 = MFMA16(gk1, fqh1, MFMA16(gk0, fqh0, z));
      f32x4 c1 = MFMA16(gk1, fql1, MFMA16(gk0, fql0, z));
      f32x4 c2 = MFMA16(gl1, fqh1, MFMA16(gl0, fqh0, z));
      sb = c0 + c1 + c2;
    }
    // causal mask: key = j0 (+16) + lg*4+i, q = q0 + lr
#pragma unroll
    for (int i = 0; i < 4; ++i) {
      if (j0 + lg * 4 + i > q0 + lr) sa[i] = NEG;
      if (j0 + 16 + lg * 4 + i > q0 + lr) sb[i] = NEG;
    }
    // in-register online softmax for q-row lr (4 lg-lanes cooperate)
    float t = fmaxf(fmaxf(fmaxf(sa[0], sa[1]), fmaxf(sa[2], sa[3])),
                    fmaxf(fmaxf(sb[0], sb[1]), fmaxf(sb[2], sb[3])));
    t = fmaxf(t, __shfl_xor(t, 16, 64));
    t = fmaxf(t, __shfl_xor(t, 32, 64));
    const float mn = fmaxf(m_s, t);
    const float sc = __expf(m_s - mn);
    m_s = mn;
    const float pa0 = __expf(sa[0] - mn), pa1 = __expf(sa[1] - mn);
    const float pa2 = __expf(sa[2] - mn), pa3 = __expf(sa[3] - mn);
    const float pb0 = __expf(sb[0] - mn), pb1 = __expf(sb[1] - mn);
    const float pb2 = __expf(sb[2] - mn), pb3 = __expf(sb[3] - mn);
    su_s = su_s * sc + ((pa0 + pa1) + (pa2 + pa3)) +
           ((pb0 + pb1) + (pb2 + pb3));
    // per-output-row rescale (output row = q0+lg*4+i; its sc lives at lane
    // lg*4+i, which has lr==lg*4+i)
#pragma unroll
    for (int i = 0; i < 4; ++i) {
      const float scr = __shfl(sc, lg * 4 + i, 64);
      o0[i] *= scr; o1[i] *= scr; o2[i] *= scr; o3[i] *= scr;
    }
    // pack P to bf16 pairs and block-transpose to the PV A-fragment:
    // target lane lg needs keys lg*8..lg*8+7 of q-row lr.
    const unsigned x0 = pk2(pa0, pa1), x1 = pk2(pa2, pa3);
    const unsigned y0 = pk2(pb0, pb1), y1 = pk2(pb2, pb3);
    const bool e = (lg & 1) != 0;
    const unsigned s0 = e ? x0 : y0, s1 = e ? x1 : y1;
    const unsigned r0 = __shfl_xor(s0, 16, 64);
    const unsigned r1 = __shfl_xor(s1, 16, 64);
    unsigned z0 = e ? r0 : x0;
    unsigned z1 = e ? r1 : x1;
    unsigned z2 = e ? y0 : r0;
    unsigned z3 = e ? y1 : r1;
    const unsigned u0 = __shfl_xor(z0, 48, 64);
    const unsigned u1 = __shfl_xor(z1, 48, 64);
    const unsigned u2 = __shfl_xor(z2, 48, 64);
    const unsigned u3 = __shfl_xor(z3, 48, 64);
    const bool sw = (lg == 1) || (lg == 2);
    z0 = sw ? u0 : z0; z1 = sw ? u1 : z1;
    z2 = sw ? u2 : z2; z3 = sw ? u3 : z3;
    union { unsigned u[4]; bf16x8 v; } pfu;
    pfu.u[0] = z0; pfu.u[1] = z1; pfu.u[2] = z2; pfu.u[3] = z3;
    const bf16x8 pf = pfu.v;
    // PV (pf straight from registers; no LDS round-trip)
    o0 = MFMA16(pf, v0, o0);
    o1 = MFMA16(pf, v1, o1);
    o2 = MFMA16(pf, v2, o2);
    o3 = MFMA16(pf, v3, o3);
  }

  // per-output-row final running max; full row denom (sum over 4 lg-lanes)
  float m_or[4];
#pragma unroll
  for (int i = 0; i < 4; ++i) m_or[i] = __shfl(m_s, lg * 4 + i, 64);
  float su_row = su_s;
  su_row += __shfl_xor(su_row, 16, 64);
  su_row += __shfl_xor(su_row, 32, 64);

  // ------- two-stage LSE merge of the 8 per-wave partials -------
  if (l < 16) {  // lg==0 lanes cover lr=0..15
    Sm[w][l] = m_s;
    Sl[w][l] = su_row;
  }
  __syncthreads();
  float M_or[4];
#pragma unroll
  for (int i = 0; i < 4; ++i) {
    const int row = lg * 4 + i;
    float M = NEG;
#pragma unroll
    for (int w2 = 0; w2 < 8; ++w2) M = fmaxf(M, Sm[w2][row]);
    M_or[i] = M;
    const float sc = __expf(m_or[i] - M);  // 0 if this wave was idle
    o0[i] *= sc; o1[i] *= sc; o2[i] *= sc; o3[i] *= sc;
    if (w == 0 && lr == 0) {
      float denom = 0.f;
#pragma unroll
      for (int w2 = 0; w2 < 8; ++w2)
        denom += Sl[w2][row] * __expf(Sm[w2][row] - M);
      Dinv[row] = 1.0f / denom;
    }
  }
  // stage 1: waves 4..7 deposit scaled O
  if (w >= 4) {
#pragma unroll
    for (int i = 0; i < 4; ++i) {
      const int row = lg * 4 + i;
      OB4[w - 4][row][lr] = o0[i];
      OB4[w - 4][row][16 + lr] = o1[i];
      OB4[w - 4][row][32 + lr] = o2[i];
      OB4[w - 4][row][48 + lr] = o3[i];
    }
  }
  __syncthreads();
  // stage 2: waves 0..3 add partner's deposit, write back to same slot
  if (w < 4) {
#pragma unroll
    for (int i = 0; i < 4; ++i) {
      const int row = lg * 4 + i;
      OB4[w][row][lr] = o0[i] + OB4[w][row][lr];
      OB4[w][row][16 + lr] = o1[i] + OB4[w][row][16 + lr];
      OB4[w][row][32 + lr] = o2[i] + OB4[w][row][32 + lr];
      OB4[w][row][48 + lr] = o3[i] + OB4[w][row][48 + lr];
    }
  }
  __syncthreads();
  // final: sum 4 slots, normalize, store (1024 elems, 512 threads)
  const int t2 = threadIdx.x;
#pragma unroll
  for (int k2 = 0; k2 < 2; ++k2) {
    const int e2 = t2 + 512 * k2;
    const int row = e2 >> 6, col = e2 & 63;
    const float s = OB4[0][row][col] + OB4[1][row][col] + OB4[2][row][col] +
                    OB4[3][row][col];
    out[((size_t)b * TT + q0 + row) * 64 + col] = s * Dinv[row];
  }
}

// ------------------------------------------------------------------ launch ---
extern "C" void kernel_launch(void* const* d_in, const int* in_sizes, int n_in,
                              void* d_out, int out_size, void* d_ws,
                              size_t ws_size, hipStream_t stream) {
  const float* x = (const float*)d_in[0];
  const float* Wq = (const float*)d_in[1];
  const float* Wk = (const float*)d_in[2];
  const float* Wv = (const float*)d_in[3];
  float* out = (float*)d_out;
  char* ws = (char*)d_ws;

  size_t off = 0;
  __bf16* WC = (__bf16*)(ws + off); off += (size_t)8 * WSLICE * 2;  // 655KB
  __bf16* qh = (__bf16*)(ws + off); off += (size_t)NROW * 64 * 2;
  __bf16* ql = (__bf16*)(ws + off); off += (size_t)NROW * 64 * 2;
  __bf16* kh = (__bf16*)(ws + off); off += (size_t)NROW * 64 * 2;
  __bf16* kl = (__bf16*)(ws + off); off += (size_t)NROW * 64 * 2;
  __bf16* vt = (__bf16*)(ws + off); off += (size_t)NROW * 64 * 2;  // ~11.1 MB

  wprep_kernel<<<dim3(32), dim3(256), 0, stream>>>(Wq, Wk, Wv, WC);
  proj_kernel<<<dim3(512), dim3(512), 0, stream>>>(
      x, WC, qh, ql, kh, kl, vt);
  attn_kernel<<<dim3(1024), dim3(512), 0, stream>>>(
      qh, ql, kh, kl, vt, out);
}

// Round 10
// 145.546 us; speedup vs baseline: 1.2747x; 1.2747x over previous
//
#include <hip/hip_runtime.h>
#include <hip/hip_bf16.h>

// MaskedAttention: out = softmax(tril(q k^T)) v, q/k/v = x @ W{q,k,v}
// B=8 T=2048 D=1024 H=64, fp32 in/out, no 1/sqrt(H) scaling.
//
// Precision plan: q,k projections and QK^T use hi/lo bf16 splitting
// (3-MFMA "bf16x3") so logits are ~fp32-accurate; V/P plain bf16.

typedef __bf16 bf16x8 __attribute__((ext_vector_type(8)));
typedef float f32x4 __attribute__((ext_vector_type(4)));

#define MFMA16(a, b, c) __builtin_amdgcn_mfma_f32_16x16x32_bf16((a), (b), (c), 0, 0, 0)
#define SB0() __builtin_amdgcn_sched_barrier(0)

static constexpr int BB = 8;
static constexpr int TT = 2048;
static constexpr int DD = 1024;
static constexpr int HH = 64;
static constexpr int NROW = BB * TT;       // 16384
// WC slab: [4 colgroups][2 K-halves][320 rows = k8l*5+frag][16 cols][8 bf16]
// frag: 0=q_hi 1=q_lo 2=k_hi 3=k_lo 4=v_hi. 80KB per (cg,half) slice.
static constexpr int WSLICE = 320 * 128;   // bf16 elems per (cg,half) = 80KB

// pack two floats to one u32 of 2 bf16 (lo, hi)
__device__ __forceinline__ unsigned pk2(float a, float b) {
  union { __bf16 h[2]; unsigned u; } r;
  r.h[0] = (__bf16)a;
  r.h[1] = (__bf16)b;
  return r.u;
}

// ---------------------------------------------------------------- W prep ---
// W [1024][64] fp32 -> WC slab (see above). Linear in (row,col) so proj can
// stage it to LDS with pure linear global_load_lds DMA.
__global__ __launch_bounds__(256) void wprep_kernel(
    const float* __restrict__ Wq, const float* __restrict__ Wk,
    const float* __restrict__ Wv, __bf16* __restrict__ WC) {
  int tid = blockIdx.x * 256 + threadIdx.x;
  if (tid >= 64 * 128) return;
  int col = tid >> 7;
  int k8 = tid & 127;
  const int g = col >> 4, c = col & 15;
  const int h2 = k8 >> 6, k8l = k8 & 63;
  bf16x8 q_h, q_l, k_h, k_l, v_h;
#pragma unroll
  for (int j = 0; j < 8; ++j) {
    const int k = k8 * 8 + j;
    float qv = Wq[k * 64 + col];
    float kv = Wk[k * 64 + col];
    float vv = Wv[k * 64 + col];
    __bf16 qhi = (__bf16)qv;
    __bf16 khi = (__bf16)kv;
    q_h[j] = qhi;
    q_l[j] = (__bf16)(qv - (float)qhi);
    k_h[j] = khi;
    k_l[j] = (__bf16)(kv - (float)khi);
    v_h[j] = (__bf16)vv;
  }
  __bf16* base = WC + (size_t)(g * 2 + h2) * WSLICE + (size_t)(k8l * 5) * 128 + c * 8;
  *(bf16x8*)(base) = q_h;            // row k8l*5+0
  *(bf16x8*)(base + 128) = q_l;      // row k8l*5+1
  *(bf16x8*)(base + 256) = k_h;      // row k8l*5+2
  *(bf16x8*)(base + 384) = k_l;      // row k8l*5+3
  *(bf16x8*)(base + 512) = v_h;      // row k8l*5+4
}

// ------------------------------------------------------------ projection ---
// Block = 512 threads (8 waves): 128 rows x ONE 16-col group, K in 2 halves.
// Per half: stage the 80KB W slice into LDS (10x global_load_lds dwordx4
// per thread, one barrier) -- all 8 waves share it. Main loop: per 32-K
// step, 2 x-loads (depth-4 rotation + SB0), 5 conflict-free ds_read_b128,
// 7 MFMA. Grid 512: rg=bid&127, cg=bid>>7 -> same-x blocks share an XCD L2.
__global__ __launch_bounds__(512, 4) void proj_kernel(
    const float* __restrict__ x, const __bf16* __restrict__ WC,
    __bf16* __restrict__ qh, __bf16* __restrict__ ql,
    __bf16* __restrict__ kh, __bf16* __restrict__ kl,
    __bf16* __restrict__ vt) {
  __shared__ __bf16 Wlds[WSLICE];  // 80 KB
  const int tid = threadIdx.x;
  const int w = tid >> 6, l = tid & 63;
  const int lr = l & 15, lg = l >> 4;
  const int rg = blockIdx.x & 127, cg = blockIdx.x >> 7;
  const int r0 = rg * 128 + w * 16;

  const float* xp = x + (size_t)(r0 + lr) * DD + lg * 8;
  // per-frag LDS base (bf16 elems): row (5*lg+m), chunk lr
  const int wb0 = (5 * lg + 0) * 128 + lr * 8;

  f32x4 aq = {0.f, 0.f, 0.f, 0.f};
  f32x4 ak = {0.f, 0.f, 0.f, 0.f};
  f32x4 av = {0.f, 0.f, 0.f, 0.f};
  float4 xa[4], xb[4];

#define LDX(J, OFF)                               \
  do {                                            \
    xa[J] = *(const float4*)(xp + (OFF));         \
    xb[J] = *(const float4*)(xp + (OFF) + 4);     \
  } while (0)

#define CMPW(J, S)                                                    \
  do {                                                                \
    const __bf16* fp = &Wlds[(S) * 2560 + wb0];                       \
    bf16x8 f0 = *(const bf16x8*)(fp);                                 \
    bf16x8 f1 = *(const bf16x8*)(fp + 128);                           \
    bf16x8 f2 = *(const bf16x8*)(fp + 256);                           \
    bf16x8 f3 = *(const bf16x8*)(fp + 384);                           \
    bf16x8 f4 = *(const bf16x8*)(fp + 512);                           \
    float xs[8] = {xa[J].x, xa[J].y, xa[J].z, xa[J].w,                \
                   xb[J].x, xb[J].y, xb[J].z, xb[J].w};               \
    bf16x8 ah, al;                                                    \
    _Pragma("unroll") for (int j = 0; j < 8; ++j) {                   \
      __bf16 hv = (__bf16)xs[j];                                      \
      ah[j] = hv;                                                     \
      al[j] = (__bf16)(xs[j] - (float)hv);                            \
    }                                                                 \
    aq = MFMA16(ah, f0, aq);                                          \
    aq = MFMA16(ah, f1, aq);                                          \
    aq = MFMA16(al, f0, aq);                                          \
    ak = MFMA16(ah, f2, ak);                                          \
    ak = MFMA16(ah, f3, ak);                                          \
    ak = MFMA16(al, f2, ak);                                          \
    av = MFMA16(ah, f4, av);                                          \
  } while (0)

#pragma unroll 1
  for (int h = 0; h < 2; ++h) {
    if (h) __syncthreads();  // all waves done reading half-0 W
    {
      const __bf16* wsrc = WC + (size_t)(cg * 2 + h) * WSLICE;
      const __bf16* gp = wsrc + (size_t)tid * 8;  // per-lane 16B cell
#pragma unroll
      for (int i2 = 0; i2 < 10; ++i2) {
        __builtin_amdgcn_global_load_lds(
            (const __attribute__((address_space(1))) unsigned int*)(gp + i2 * 4096),
            (__attribute__((address_space(3))) unsigned int*)
                ((char*)Wlds + w * 1024 + i2 * 8192),
            16, 0, 0);
      }
    }
    __syncthreads();  // compiler drains vmcnt before barrier: DMA complete

    const int xoff = h * 512;
    LDX(0, xoff); LDX(1, xoff + 32); LDX(2, xoff + 64); LDX(3, xoff + 96);
    SB0();
#pragma unroll
    for (int s = 0; s < 16; ++s) {
      CMPW(s & 3, s);
      if (s < 12) LDX(s & 3, xoff + (s + 4) * 32);
      SB0();
    }
  }
#undef LDX
#undef CMPW

#pragma unroll
  for (int i = 0; i < 4; ++i) {
    const int row = r0 + lg * 4 + i;  // C-layout: row=(lane>>4)*4+reg
    const int col = cg * 16 + lr;     //           col=lane&15
    const size_t oq = (size_t)row * 64 + col;
    float qv = aq[i];
    __bf16 qhi = (__bf16)qv;
    qh[oq] = qhi;
    ql[oq] = (__bf16)(qv - (float)qhi);
    float kv = ak[i];
    __bf16 khi = (__bf16)kv;
    kh[oq] = khi;
    kl[oq] = (__bf16)(kv - (float)khi);
    const int bb = row >> 11, tt = row & 2047;
    vt[((size_t)bb * 64 + col) * 2048 + tt] = (__bf16)av[i];
  }
}

// -------------------------------------------------------------- attention ---
// Split-K flash, 4-wave blocks (R8 base: 63.4us, 56 VGPR, 0 conflicts),
// now SOFTWARE-PIPELINED depth 2. R9 post-mortem: 8-wave + 64-VGPR cap
// spills (twice confirmed) -- 4-wave blocks are the law. R8's residual
// stall: all 12 loads of iter n issued at top of iter n, QK waits
// immediately -> full L2 latency per iter. Now: two named register sets,
// K(n+1) issued before softmax(n), V(n+1) before softmax(n+1) -> every
// load covered by >=1 compute phase. Invariants: 1024 blocks all resident
// (4/CU), b=bid&7 XCD affinity, (256,4) = 128-VGPR budget, no spill.
__global__ __launch_bounds__(256, 4) void attn_kernel(
    const __bf16* __restrict__ qh, const __bf16* __restrict__ ql,
    const __bf16* __restrict__ kh, const __bf16* __restrict__ kl,
    const __bf16* __restrict__ vt, float* __restrict__ out) {
  __shared__ float Sm[4][16];       // per-wave row maxes
  __shared__ float Sl[4][16];       // per-wave row sums
  __shared__ float OB[4][16][68];   // per-wave scaled O (68 pad: <=2-way, free)
  __shared__ float Dinv[16];        // 1/denom per row
  const int w = threadIdx.x >> 6, l = threadIdx.x & 63;
  const int lr = l & 15, lg = l >> 4;
  const int b = blockIdx.x & 7;            // XCD affinity: batch -> XCD
  const int qt = 127 - (blockIdx.x >> 3);  // heavy tiles first
  const int q0 = qt * 16;
  const float NEG = -__builtin_inff();

  // Q fragments (B-operand of the swapped QK^T)
  const size_t qb = ((size_t)b * TT + q0 + lr) * 64 + lg * 8;
  const bf16x8 fqh0 = *(const bf16x8*)(qh + qb);
  const bf16x8 fqh1 = *(const bf16x8*)(qh + qb + 32);
  const bf16x8 fql0 = *(const bf16x8*)(ql + qb);
  const bf16x8 fql1 = *(const bf16x8*)(ql + qb + 32);

  f32x4 o0 = {0.f, 0.f, 0.f, 0.f}, o1 = o0, o2 = o0, o3 = o0;
  float m_s = NEG;   // running max for q-row (q0+lr), shared by 4 lg-lanes
  float su_s = 0.f;  // partial denom for q-row (this lane's keys only)
  const int nkt = (q0 + 47) >> 5;  // ceil((q0+16)/32)

  // two named register sets (rule #20: no runtime-indexed arrays)
  bf16x8 fk00, fk10, fl00, fl10, gk00, gk10, gl00, gl10;
  bf16x8 fk01, fk11, fl01, fl11, gk01, gk11, gl01, gl11;
  bf16x8 v00, v10, v20, v30, v01, v11, v21, v31;
  f32x4 sa, sb;

#define LDK(S, KT)                                                     \
  do {                                                                 \
    const int j0_ = (KT) * 32;                                         \
    const size_t kbA_ = ((size_t)b * TT + j0_ + lr) * 64 + lg * 8;     \
    const size_t kbB_ = kbA_ + (size_t)16 * 64;                        \
    fk0##S = *(const bf16x8*)(kh + kbA_);                              \
    fk1##S = *(const bf16x8*)(kh + kbA_ + 32);                         \
    fl0##S = *(const bf16x8*)(kl + kbA_);                              \
    fl1##S = *(const bf16x8*)(kl + kbA_ + 32);                         \
    gk0##S = *(const bf16x8*)(kh + kbB_);                              \
    gk1##S = *(const bf16x8*)(kh + kbB_ + 32);                         \
    gl0##S = *(const bf16x8*)(kl + kbB_);                              \
    gl1##S = *(const bf16x8*)(kl + kbB_ + 32);                         \
  } while (0)

#define LDV(S, KT)                                                     \
  do {                                                                 \
    const size_t vb_ =                                                 \
        ((size_t)b * 64 + lr) * 2048 + (KT) * 32 + lg * 8;             \
    v0##S = *(const bf16x8*)(vt + vb_);                                \
    v1##S = *(const bf16x8*)(vt + vb_ + (size_t)16 * 2048);            \
    v2##S = *(const bf16x8*)(vt + vb_ + (size_t)32 * 2048);            \
    v3##S = *(const bf16x8*)(vt + vb_ + (size_t)48 * 2048);            \
  } while (0)

#define QKM(S, KT)                                                     \
  do {                                                                 \
    const int j0_ = (KT) * 32;                                         \
    const f32x4 z_ = {0.f, 0.f, 0.f, 0.f};                             \
    {                                                                  \
      f32x4 c0_ = MFMA16(fk1##S, fqh1, MFMA16(fk0##S, fqh0, z_));      \
      f32x4 c1_ = MFMA16(fk1##S, fql1, MFMA16(fk0##S, fql0, z_));      \
      f32x4 c2_ = MFMA16(fl1##S, fqh1, MFMA16(fl0##S, fqh0, z_));      \
      sa = c0_ + c1_ + c2_;                                            \
    }                                                                  \
    sb = (f32x4){NEG, NEG, NEG, NEG};                                  \
    if ((j0_ + 16) <= (q0 + 15)) {                                     \
      f32x4 c0_ = MFMA16(gk1##S, fqh1, MFMA16(gk0##S, fqh0, z_));      \
      f32x4 c1_ = MFMA16(gk1##S, fql1, MFMA16(gk0##S, fql0, z_));      \
      f32x4 c2_ = MFMA16(gl1##S, fqh1, MFMA16(gl0##S, fqh0, z_));      \
      sb = c0_ + c1_ + c2_;                                            \
    }                                                                  \
    _Pragma("unroll") for (int i = 0; i < 4; ++i) {                    \
      if (j0_ + lg * 4 + i > q0 + lr) sa[i] = NEG;                     \
      if (j0_ + 16 + lg * 4 + i > q0 + lr) sb[i] = NEG;                \
    }                                                                  \
  } while (0)

#define SPV(S)                                                         \
  do {                                                                 \
    float t_ = fmaxf(fmaxf(fmaxf(sa[0], sa[1]), fmaxf(sa[2], sa[3])),  \
                     fmaxf(fmaxf(sb[0], sb[1]), fmaxf(sb[2], sb[3]))); \
    t_ = fmaxf(t_, __shfl_xor(t_, 16, 64));                            \
    t_ = fmaxf(t_, __shfl_xor(t_, 32, 64));                            \
    const float mn_ = fmaxf(m_s, t_);                                  \
    const float sc_ = __expf(m_s - mn_);                               \
    m_s = mn_;                                                         \
    const float pa0_ = __expf(sa[0] - mn_), pa1_ = __expf(sa[1] - mn_);\
    const float pa2_ = __expf(sa[2] - mn_), pa3_ = __expf(sa[3] - mn_);\
    const float pb0_ = __expf(sb[0] - mn_), pb1_ = __expf(sb[1] - mn_);\
    const float pb2_ = __expf(sb[2] - mn_), pb3_ = __expf(sb[3] - mn_);\
    su_s = su_s * sc_ + ((pa0_ + pa1_) + (pa2_ + pa3_)) +              \
           ((pb0_ + pb1_) + (pb2_ + pb3_));                            \
    _Pragma("unroll") for (int i = 0; i < 4; ++i) {                    \
      const float scr_ = __shfl(sc_, lg * 4 + i, 64);                  \
      o0[i] *= scr_; o1[i] *= scr_; o2[i] *= scr_; o3[i] *= scr_;      \
    }                                                                  \
    const unsigned x0_ = pk2(pa0_, pa1_), x1_ = pk2(pa2_, pa3_);       \
    const unsigned y0_ = pk2(pb0_, pb1_), y1_ = pk2(pb2_, pb3_);       \
    const bool e_ = (lg & 1) != 0;                                     \
    const unsigned s0_ = e_ ? x0_ : y0_, s1_ = e_ ? x1_ : y1_;         \
    const unsigned r0_ = __shfl_xor(s0_, 16, 64);                      \
    const unsigned r1_ = __shfl_xor(s1_, 16, 64);                      \
    unsigned z0_ = e_ ? r0_ : x0_;                                     \
    unsigned z1_ = e_ ? r1_ : x1_;                                     \
    unsigned z2_ = e_ ? y0_ : r0_;                                     \
    unsigned z3_ = e_ ? y1_ : r1_;                                     \
    const unsigned u0_ = __shfl_xor(z0_, 48, 64);                      \
    const unsigned u1_ = __shfl_xor(z1_, 48, 64);                      \
    const unsigned u2_ = __shfl_xor(z2_, 48, 64);                      \
    const unsigned u3_ = __shfl_xor(z3_, 48, 64);                      \
    const bool sw_ = (lg == 1) || (lg == 2);                           \
    z0_ = sw_ ? u0_ : z0_; z1_ = sw_ ? u1_ : z1_;                      \
    z2_ = sw_ ? u2_ : z2_; z3_ = sw_ ? u3_ : z3_;                      \
    union { unsigned u[4]; bf16x8 v; } pfu_;                           \
    pfu_.u[0] = z0_; pfu_.u[1] = z1_;                                  \
    pfu_.u[2] = z2_; pfu_.u[3] = z3_;                                  \
    const bf16x8 pf_ = pfu_.v;                                         \
    o0 = MFMA16(pf_, v0##S, o0);                                       \
    o1 = MFMA16(pf_, v1##S, o1);                                       \
    o2 = MFMA16(pf_, v2##S, o2);                                       \
    o3 = MFMA16(pf_, v3##S, o3);                                       \
  } while (0)

  int kt = w;
  if (kt < nkt) {
    LDK(0, kt);
    LDV(0, kt);
    SB0();
  }
#pragma unroll 1
  for (; kt + 4 < nkt; kt += 8) {
    LDK(1, kt + 4); SB0();       // next K in flight across softmax+PV(cur)
    QKM(0, kt);                  // K(cur) loaded >=1 phase ago
    LDV(1, kt + 4); SB0();       // next V in flight across PV(cur)+QK(next)
    SPV(0);
    if (kt + 8 < nkt) { LDK(0, kt + 8); SB0(); }
    QKM(1, kt + 4);
    if (kt + 8 < nkt) { LDV(0, kt + 8); SB0(); }
    SPV(1);
  }
  if (kt < nkt) {  // tail tile (set 0 already loaded)
    QKM(0, kt);
    SPV(0);
  }
#undef LDK
#undef LDV
#undef QKM
#undef SPV

  // per-output-row final running max; full row denom (sum over 4 lg-lanes)
  float m_or[4];
#pragma unroll
  for (int i = 0; i < 4; ++i) m_or[i] = __shfl(m_s, lg * 4 + i, 64);
  float su_row = su_s;
  su_row += __shfl_xor(su_row, 16, 64);
  su_row += __shfl_xor(su_row, 32, 64);

  // ------- LSE merge of the 4 per-wave partials -------
  if (l < 16) {  // lg==0 lanes cover lr=0..15
    Sm[w][l] = m_s;
    Sl[w][l] = su_row;
  }
  __syncthreads();
#pragma unroll
  for (int i = 0; i < 4; ++i) {
    const int row = lg * 4 + i;
    float M = fmaxf(fmaxf(Sm[0][row], Sm[1][row]),
                    fmaxf(Sm[2][row], Sm[3][row]));
    const float sc = __expf(m_or[i] - M);  // 0 if this wave was idle
    OB[w][row][lr] = o0[i] * sc;
    OB[w][row][16 + lr] = o1[i] * sc;
    OB[w][row][32 + lr] = o2[i] * sc;
    OB[w][row][48 + lr] = o3[i] * sc;
    if (w == 0 && lr == 0) {
      float denom = 0.f;
#pragma unroll
      for (int w2 = 0; w2 < 4; ++w2)
        denom += Sl[w2][row] * __expf(Sm[w2][row] - M);
      Dinv[row] = 1.0f / denom;
    }
  }
  __syncthreads();
  const int t2 = threadIdx.x;
#pragma unroll
  for (int k2 = 0; k2 < 4; ++k2) {
    const int e2 = t2 + 256 * k2;
    const int row = e2 >> 6, col = e2 & 63;
    const float s = OB[0][row][col] + OB[1][row][col] + OB[2][row][col] +
                    OB[3][row][col];
    out[((size_t)b * TT + q0 + row) * 64 + col] = s * Dinv[row];
  }
}

// ------------------------------------------------------------------ launch ---
extern "C" void kernel_launch(void* const* d_in, const int* in_sizes, int n_in,
                              void* d_out, int out_size, void* d_ws,
                              size_t ws_size, hipStream_t stream) {
  const float* x = (const float*)d_in[0];
  const float* Wq = (const float*)d_in[1];
  const float* Wk = (const float*)d_in[2];
  const float* Wv = (const float*)d_in[3];
  float* out = (float*)d_out;
  char* ws = (char*)d_ws;

  size_t off = 0;
  __bf16* WC = (__bf16*)(ws + off); off += (size_t)8 * WSLICE * 2;  // 655KB
  __bf16* qh = (__bf16*)(ws + off); off += (size_t)NROW * 64 * 2;
  __bf16* ql = (__bf16*)(ws + off); off += (size_t)NROW * 64 * 2;
  __bf16* kh = (__bf16*)(ws + off); off += (size_t)NROW * 64 * 2;
  __bf16* kl = (__bf16*)(ws + off); off += (size_t)NROW * 64 * 2;
  __bf16* vt = (__bf16*)(ws + off); off += (size_t)NROW * 64 * 2;  // ~11.1 MB

  wprep_kernel<<<dim3(32), dim3(256), 0, stream>>>(Wq, Wk, Wv, WC);
  proj_kernel<<<dim3(512), dim3(512), 0, stream>>>(
      x, WC, qh, ql, kh, kl, vt);
  attn_kernel<<<dim3(1024), dim3(256), 0, stream>>>(
      qh, ql, kh, kl, vt, out);
}

// Round 11
// 111.674 us; speedup vs baseline: 1.6614x; 1.3033x over previous
//
#include <hip/hip_runtime.h>
#include <hip/hip_bf16.h>

// MaskedAttention: out = softmax(tril(q k^T)) v, q/k/v = x @ W{q,k,v}
// B=8 T=2048 D=1024 H=64, fp32 in/out, no 1/sqrt(H) scaling.
//
// Precision plan: q,k projections and QK^T use hi/lo bf16 splitting
// (3-MFMA "bf16x3") so logits are ~fp32-accurate; V/P plain bf16.

typedef __bf16 bf16x8 __attribute__((ext_vector_type(8)));
typedef float f32x4 __attribute__((ext_vector_type(4)));

#define MFMA16(a, b, c) __builtin_amdgcn_mfma_f32_16x16x32_bf16((a), (b), (c), 0, 0, 0)
#define SB0() __builtin_amdgcn_sched_barrier(0)

static constexpr int BB = 8;
static constexpr int TT = 2048;
static constexpr int DD = 1024;
static constexpr int HH = 64;
static constexpr int NROW = BB * TT;       // 16384
// WC slab: [4 colgroups][2 K-halves][320 rows = k8l*5+frag][16 cols][8 bf16]
// frag: 0=q_hi 1=q_lo 2=k_hi 3=k_lo 4=v_hi. 80KB per (cg,half) slice.
static constexpr int WSLICE = 320 * 128;   // bf16 elems per (cg,half) = 80KB

// pack two floats to one u32 of 2 bf16 (lo, hi)
__device__ __forceinline__ unsigned pk2(float a, float b) {
  union { __bf16 h[2]; unsigned u; } r;
  r.h[0] = (__bf16)a;
  r.h[1] = (__bf16)b;
  return r.u;
}

// ---------------------------------------------------------------- W prep ---
// W [1024][64] fp32 -> WC slab (see above). Linear in (row,col) so proj can
// stage it to LDS with pure linear global_load_lds DMA.
__global__ __launch_bounds__(256) void wprep_kernel(
    const float* __restrict__ Wq, const float* __restrict__ Wk,
    const float* __restrict__ Wv, __bf16* __restrict__ WC) {
  int tid = blockIdx.x * 256 + threadIdx.x;
  if (tid >= 64 * 128) return;
  int col = tid >> 7;
  int k8 = tid & 127;
  const int g = col >> 4, c = col & 15;
  const int h2 = k8 >> 6, k8l = k8 & 63;
  bf16x8 q_h, q_l, k_h, k_l, v_h;
#pragma unroll
  for (int j = 0; j < 8; ++j) {
    const int k = k8 * 8 + j;
    float qv = Wq[k * 64 + col];
    float kv = Wk[k * 64 + col];
    float vv = Wv[k * 64 + col];
    __bf16 qhi = (__bf16)qv;
    __bf16 khi = (__bf16)kv;
    q_h[j] = qhi;
    q_l[j] = (__bf16)(qv - (float)qhi);
    k_h[j] = khi;
    k_l[j] = (__bf16)(kv - (float)khi);
    v_h[j] = (__bf16)vv;
  }
  __bf16* base = WC + (size_t)(g * 2 + h2) * WSLICE + (size_t)(k8l * 5) * 128 + c * 8;
  *(bf16x8*)(base) = q_h;            // row k8l*5+0
  *(bf16x8*)(base + 128) = q_l;      // row k8l*5+1
  *(bf16x8*)(base + 256) = k_h;      // row k8l*5+2
  *(bf16x8*)(base + 384) = k_l;      // row k8l*5+3
  *(bf16x8*)(base + 512) = v_h;      // row k8l*5+4
}

// ------------------------------------------------------------ projection ---
// Block = 512 threads (8 waves): 128 rows x ONE 16-col group, K in 2 halves.
// Per half: stage the 80KB W slice into LDS (10x global_load_lds dwordx4
// per thread, one barrier) -- all 8 waves share it. Main loop: per 32-K
// step, 2 x-loads (depth-4 rotation + SB0), 5 conflict-free ds_read_b128,
// 7 MFMA. Grid 512: rg=bid&127, cg=bid>>7 -> same-x blocks share an XCD L2.
__global__ __launch_bounds__(512, 4) void proj_kernel(
    const float* __restrict__ x, const __bf16* __restrict__ WC,
    __bf16* __restrict__ qh, __bf16* __restrict__ ql,
    __bf16* __restrict__ kh, __bf16* __restrict__ kl,
    __bf16* __restrict__ vt) {
  __shared__ __bf16 Wlds[WSLICE];  // 80 KB
  const int tid = threadIdx.x;
  const int w = tid >> 6, l = tid & 63;
  const int lr = l & 15, lg = l >> 4;
  const int rg = blockIdx.x & 127, cg = blockIdx.x >> 7;
  const int r0 = rg * 128 + w * 16;

  const float* xp = x + (size_t)(r0 + lr) * DD + lg * 8;
  // per-frag LDS base (bf16 elems): row (5*lg+m), chunk lr
  const int wb0 = (5 * lg + 0) * 128 + lr * 8;

  f32x4 aq = {0.f, 0.f, 0.f, 0.f};
  f32x4 ak = {0.f, 0.f, 0.f, 0.f};
  f32x4 av = {0.f, 0.f, 0.f, 0.f};
  float4 xa[4], xb[4];

#define LDX(J, OFF)                               \
  do {                                            \
    xa[J] = *(const float4*)(xp + (OFF));         \
    xb[J] = *(const float4*)(xp + (OFF) + 4);     \
  } while (0)

#define CMPW(J, S)                                                    \
  do {                                                                \
    const __bf16* fp = &Wlds[(S) * 2560 + wb0];                       \
    bf16x8 f0 = *(const bf16x8*)(fp);                                 \
    bf16x8 f1 = *(const bf16x8*)(fp + 128);                           \
    bf16x8 f2 = *(const bf16x8*)(fp + 256);                           \
    bf16x8 f3 = *(const bf16x8*)(fp + 384);                           \
    bf16x8 f4 = *(const bf16x8*)(fp + 512);                           \
    float xs[8] = {xa[J].x, xa[J].y, xa[J].z, xa[J].w,                \
                   xb[J].x, xb[J].y, xb[J].z, xb[J].w};               \
    bf16x8 ah, al;                                                    \
    _Pragma("unroll") for (int j = 0; j < 8; ++j) {                   \
      __bf16 hv = (__bf16)xs[j];                                      \
      ah[j] = hv;                                                     \
      al[j] = (__bf16)(xs[j] - (float)hv);                            \
    }                                                                 \
    aq = MFMA16(ah, f0, aq);                                          \
    aq = MFMA16(ah, f1, aq);                                          \
    aq = MFMA16(al, f0, aq);                                          \
    ak = MFMA16(ah, f2, ak);                                          \
    ak = MFMA16(ah, f3, ak);                                          \
    ak = MFMA16(al, f2, ak);                                          \
    av = MFMA16(ah, f4, av);                                          \
  } while (0)

#pragma unroll 1
  for (int h = 0; h < 2; ++h) {
    if (h) __syncthreads();  // all waves done reading half-0 W
    {
      const __bf16* wsrc = WC + (size_t)(cg * 2 + h) * WSLICE;
      const __bf16* gp = wsrc + (size_t)tid * 8;  // per-lane 16B cell
#pragma unroll
      for (int i2 = 0; i2 < 10; ++i2) {
        __builtin_amdgcn_global_load_lds(
            (const __attribute__((address_space(1))) unsigned int*)(gp + i2 * 4096),
            (__attribute__((address_space(3))) unsigned int*)
                ((char*)Wlds + w * 1024 + i2 * 8192),
            16, 0, 0);
      }
    }
    __syncthreads();  // compiler drains vmcnt before barrier: DMA complete

    const int xoff = h * 512;
    LDX(0, xoff); LDX(1, xoff + 32); LDX(2, xoff + 64); LDX(3, xoff + 96);
    SB0();
#pragma unroll
    for (int s = 0; s < 16; ++s) {
      CMPW(s & 3, s);
      if (s < 12) LDX(s & 3, xoff + (s + 4) * 32);
      SB0();
    }
  }
#undef LDX
#undef CMPW

#pragma unroll
  for (int i = 0; i < 4; ++i) {
    const int row = r0 + lg * 4 + i;  // C-layout: row=(lane>>4)*4+reg
    const int col = cg * 16 + lr;     //           col=lane&15
    const size_t oq = (size_t)row * 64 + col;
    float qv = aq[i];
    __bf16 qhi = (__bf16)qv;
    qh[oq] = qhi;
    ql[oq] = (__bf16)(qv - (float)qhi);
    float kv = ak[i];
    __bf16 khi = (__bf16)kv;
    kh[oq] = khi;
    kl[oq] = (__bf16)(kv - (float)khi);
    const int bb = row >> 11, tt = row & 2047;
    vt[((size_t)bb * 64 + col) * 2048 + tt] = (__bf16)av[i];
  }
}

// -------------------------------------------------------------- attention ---
// Split-K flash, 4-wave blocks (R8 base: 63.4us, 56 VGPR, 0 conflicts),
// with a REGISTER-FRUGAL pipeline. Ledger from R7/R9/R10: peak live must
// stay <=~110 (R10's double-set needed ~130 -> 64-reg body + 194MB spill).
// Schedule (single K set, single V set):
//   iter top: issue V(n); QK(n) consumes K(n) [prefetched last iter];
//   issue K(n+1) AFTER QK(n) (K sets never overlap); softmax+PV(n).
// K(n+1) covered by softmax+PV+next LDV (~250cy); V(n) covered by K-wait
// +QK (~100cy). Peak live ~= Q16+acc16+K32+V16+temps ~= 95 < 128.
// Invariants: 1024 blocks all resident (4/CU), b=bid&7 XCD affinity,
// (256,4) = 128-VGPR budget, NO vgpr cap (caps make the allocator spill).
__global__ __launch_bounds__(256, 4) void attn_kernel(
    const __bf16* __restrict__ qh, const __bf16* __restrict__ ql,
    const __bf16* __restrict__ kh, const __bf16* __restrict__ kl,
    const __bf16* __restrict__ vt, float* __restrict__ out) {
  __shared__ float Sm[4][16];       // per-wave row maxes
  __shared__ float Sl[4][16];       // per-wave row sums
  __shared__ float OB[4][16][68];   // per-wave scaled O (68 pad: <=2-way, free)
  __shared__ float Dinv[16];        // 1/denom per row
  const int w = threadIdx.x >> 6, l = threadIdx.x & 63;
  const int lr = l & 15, lg = l >> 4;
  const int b = blockIdx.x & 7;            // XCD affinity: batch -> XCD
  const int qt = 127 - (blockIdx.x >> 3);  // heavy tiles first
  const int q0 = qt * 16;
  const float NEG = -__builtin_inff();

  // Q fragments (B-operand of the swapped QK^T)
  const size_t qb = ((size_t)b * TT + q0 + lr) * 64 + lg * 8;
  const bf16x8 fqh0 = *(const bf16x8*)(qh + qb);
  const bf16x8 fqh1 = *(const bf16x8*)(qh + qb + 32);
  const bf16x8 fql0 = *(const bf16x8*)(ql + qb);
  const bf16x8 fql1 = *(const bf16x8*)(ql + qb + 32);

  f32x4 o0 = {0.f, 0.f, 0.f, 0.f}, o1 = o0, o2 = o0, o3 = o0;
  float m_s = NEG;   // running max for q-row (q0+lr), shared by 4 lg-lanes
  float su_s = 0.f;  // partial denom for q-row (this lane's keys only)
  const int nkt = (q0 + 47) >> 5;  // ceil((q0+16)/32)

  // single K register set + single V register set (peak-live control)
  bf16x8 fk0, fk1, fl0, fl1, gk0, gk1, gl0, gl1;
  bf16x8 v0, v1, v2, v3;
  f32x4 sa, sb;

#define LDK(KT)                                                        \
  do {                                                                 \
    const int j0_ = (KT) * 32;                                         \
    const size_t kbA_ = ((size_t)b * TT + j0_ + lr) * 64 + lg * 8;     \
    const size_t kbB_ = kbA_ + (size_t)16 * 64;                        \
    fk0 = *(const bf16x8*)(kh + kbA_);                                 \
    fk1 = *(const bf16x8*)(kh + kbA_ + 32);                            \
    fl0 = *(const bf16x8*)(kl + kbA_);                                 \
    fl1 = *(const bf16x8*)(kl + kbA_ + 32);                            \
    gk0 = *(const bf16x8*)(kh + kbB_);                                 \
    gk1 = *(const bf16x8*)(kh + kbB_ + 32);                            \
    gl0 = *(const bf16x8*)(kl + kbB_);                                 \
    gl1 = *(const bf16x8*)(kl + kbB_ + 32);                            \
  } while (0)

#define LDV(KT)                                                        \
  do {                                                                 \
    const size_t vb_ =                                                 \
        ((size_t)b * 64 + lr) * 2048 + (KT) * 32 + lg * 8;             \
    v0 = *(const bf16x8*)(vt + vb_);                                   \
    v1 = *(const bf16x8*)(vt + vb_ + (size_t)16 * 2048);               \
    v2 = *(const bf16x8*)(vt + vb_ + (size_t)32 * 2048);               \
    v3 = *(const bf16x8*)(vt + vb_ + (size_t)48 * 2048);               \
  } while (0)

#define QKM(KT)                                                        \
  do {                                                                 \
    const int j0_ = (KT) * 32;                                         \
    const f32x4 z_ = {0.f, 0.f, 0.f, 0.f};                             \
    {                                                                  \
      f32x4 c0_ = MFMA16(fk1, fqh1, MFMA16(fk0, fqh0, z_));            \
      f32x4 c1_ = MFMA16(fk1, fql1, MFMA16(fk0, fql0, z_));            \
      f32x4 c2_ = MFMA16(fl1, fqh1, MFMA16(fl0, fqh0, z_));            \
      sa = c0_ + c1_ + c2_;                                            \
    }                                                                  \
    sb = (f32x4){NEG, NEG, NEG, NEG};                                  \
    if ((j0_ + 16) <= (q0 + 15)) {                                     \
      f32x4 c0_ = MFMA16(gk1, fqh1, MFMA16(gk0, fqh0, z_));            \
      f32x4 c1_ = MFMA16(gk1, fql1, MFMA16(gk0, fql0, z_));            \
      f32x4 c2_ = MFMA16(gl1, fqh1, MFMA16(gl0, fqh0, z_));            \
      sb = c0_ + c1_ + c2_;                                            \
    }                                                                  \
    _Pragma("unroll") for (int i = 0; i < 4; ++i) {                    \
      if (j0_ + lg * 4 + i > q0 + lr) sa[i] = NEG;                     \
      if (j0_ + 16 + lg * 4 + i > q0 + lr) sb[i] = NEG;                \
    }                                                                  \
  } while (0)

#define SPV()                                                          \
  do {                                                                 \
    float t_ = fmaxf(fmaxf(fmaxf(sa[0], sa[1]), fmaxf(sa[2], sa[3])),  \
                     fmaxf(fmaxf(sb[0], sb[1]), fmaxf(sb[2], sb[3]))); \
    t_ = fmaxf(t_, __shfl_xor(t_, 16, 64));                            \
    t_ = fmaxf(t_, __shfl_xor(t_, 32, 64));                            \
    const float mn_ = fmaxf(m_s, t_);                                  \
    const float sc_ = __expf(m_s - mn_);                               \
    m_s = mn_;                                                         \
    const float pa0_ = __expf(sa[0] - mn_), pa1_ = __expf(sa[1] - mn_);\
    const float pa2_ = __expf(sa[2] - mn_), pa3_ = __expf(sa[3] - mn_);\
    const float pb0_ = __expf(sb[0] - mn_), pb1_ = __expf(sb[1] - mn_);\
    const float pb2_ = __expf(sb[2] - mn_), pb3_ = __expf(sb[3] - mn_);\
    su_s = su_s * sc_ + ((pa0_ + pa1_) + (pa2_ + pa3_)) +              \
           ((pb0_ + pb1_) + (pb2_ + pb3_));                            \
    _Pragma("unroll") for (int i = 0; i < 4; ++i) {                    \
      const float scr_ = __shfl(sc_, lg * 4 + i, 64);                  \
      o0[i] *= scr_; o1[i] *= scr_; o2[i] *= scr_; o3[i] *= scr_;      \
    }                                                                  \
    const unsigned x0_ = pk2(pa0_, pa1_), x1_ = pk2(pa2_, pa3_);       \
    const unsigned y0_ = pk2(pb0_, pb1_), y1_ = pk2(pb2_, pb3_);       \
    const bool e_ = (lg & 1) != 0;                                     \
    const unsigned s0_ = e_ ? x0_ : y0_, s1_ = e_ ? x1_ : y1_;         \
    const unsigned r0_ = __shfl_xor(s0_, 16, 64);                      \
    const unsigned r1_ = __shfl_xor(s1_, 16, 64);                      \
    unsigned z0_ = e_ ? r0_ : x0_;                                     \
    unsigned z1_ = e_ ? r1_ : x1_;                                     \
    unsigned z2_ = e_ ? y0_ : r0_;                                     \
    unsigned z3_ = e_ ? y1_ : r1_;                                     \
    const unsigned u0_ = __shfl_xor(z0_, 48, 64);                      \
    const unsigned u1_ = __shfl_xor(z1_, 48, 64);                      \
    const unsigned u2_ = __shfl_xor(z2_, 48, 64);                      \
    const unsigned u3_ = __shfl_xor(z3_, 48, 64);                      \
    const bool sw_ = (lg == 1) || (lg == 2);                           \
    z0_ = sw_ ? u0_ : z0_; z1_ = sw_ ? u1_ : z1_;                      \
    z2_ = sw_ ? u2_ : z2_; z3_ = sw_ ? u3_ : z3_;                      \
    union { unsigned u[4]; bf16x8 v; } pfu_;                           \
    pfu_.u[0] = z0_; pfu_.u[1] = z1_;                                  \
    pfu_.u[2] = z2_; pfu_.u[3] = z3_;                                  \
    const bf16x8 pf_ = pfu_.v;                                         \
    o0 = MFMA16(pf_, v0, o0);                                          \
    o1 = MFMA16(pf_, v1, o1);                                          \
    o2 = MFMA16(pf_, v2, o2);                                          \
    o3 = MFMA16(pf_, v3, o3);                                          \
  } while (0)

  if (w < nkt) LDK(w);  // prologue: first K tile in flight
#pragma unroll 1
  for (int kt = w; kt < nkt; kt += 4) {
    LDV(kt);
    SB0();               // V(n) in flight across K-wait + QK(n)
    QKM(kt);             // consumes K(n); K set now dead
    if (kt + 4 < nkt) LDK(kt + 4);
    SB0();               // K(n+1) in flight across softmax+PV(n)
    SPV();
  }
#undef LDK
#undef LDV
#undef QKM
#undef SPV

  // per-output-row final running max; full row denom (sum over 4 lg-lanes)
  float m_or[4];
#pragma unroll
  for (int i = 0; i < 4; ++i) m_or[i] = __shfl(m_s, lg * 4 + i, 64);
  float su_row = su_s;
  su_row += __shfl_xor(su_row, 16, 64);
  su_row += __shfl_xor(su_row, 32, 64);

  // ------- LSE merge of the 4 per-wave partials -------
  if (l < 16) {  // lg==0 lanes cover lr=0..15
    Sm[w][l] = m_s;
    Sl[w][l] = su_row;
  }
  __syncthreads();
#pragma unroll
  for (int i = 0; i < 4; ++i) {
    const int row = lg * 4 + i;
    float M = fmaxf(fmaxf(Sm[0][row], Sm[1][row]),
                    fmaxf(Sm[2][row], Sm[3][row]));
    const float sc = __expf(m_or[i] - M);  // 0 if this wave was idle
    OB[w][row][lr] = o0[i] * sc;
    OB[w][row][16 + lr] = o1[i] * sc;
    OB[w][row][32 + lr] = o2[i] * sc;
    OB[w][row][48 + lr] = o3[i] * sc;
    if (w == 0 && lr == 0) {
      float denom = 0.f;
#pragma unroll
      for (int w2 = 0; w2 < 4; ++w2)
        denom += Sl[w2][row] * __expf(Sm[w2][row] - M);
      Dinv[row] = 1.0f / denom;
    }
  }
  __syncthreads();
  const int t2 = threadIdx.x;
#pragma unroll
  for (int k2 = 0; k2 < 4; ++k2) {
    const int e2 = t2 + 256 * k2;
    const int row = e2 >> 6, col = e2 & 63;
    const float s = OB[0][row][col] + OB[1][row][col] + OB[2][row][col] +
                    OB[3][row][col];
    out[((size_t)b * TT + q0 + row) * 64 + col] = s * Dinv[row];
  }
}

// ------------------------------------------------------------------ launch ---
extern "C" void kernel_launch(void* const* d_in, const int* in_sizes, int n_in,
                              void* d_out, int out_size, void* d_ws,
                              size_t ws_size, hipStream_t stream) {
  const float* x = (const float*)d_in[0];
  const float* Wq = (const float*)d_in[1];
  const float* Wk = (const float*)d_in[2];
  const float* Wv = (const float*)d_in[3];
  float* out = (float*)d_out;
  char* ws = (char*)d_ws;

  size_t off = 0;
  __bf16* WC = (__bf16*)(ws + off); off += (size_t)8 * WSLICE * 2;  // 655KB
  __bf16* qh = (__bf16*)(ws + off); off += (size_t)NROW * 64 * 2;
  __bf16* ql = (__bf16*)(ws + off); off += (size_t)NROW * 64 * 2;
  __bf16* kh = (__bf16*)(ws + off); off += (size_t)NROW * 64 * 2;
  __bf16* kl = (__bf16*)(ws + off); off += (size_t)NROW * 64 * 2;
  __bf16* vt = (__bf16*)(ws + off); off += (size_t)NROW * 64 * 2;  // ~11.1 MB

  wprep_kernel<<<dim3(32), dim3(256), 0, stream>>>(Wq, Wk, Wv, WC);
  proj_kernel<<<dim3(512), dim3(512), 0, stream>>>(
      x, WC, qh, ql, kh, kl, vt);
  attn_kernel<<<dim3(1024), dim3(256), 0, stream>>>(
      qh, ql, kh, kl, vt, out);
}

// Round 12
// 83.791 us; speedup vs baseline: 2.2143x; 1.3328x over previous
//
#include <hip/hip_runtime.h>
#include <hip/hip_bf16.h>

// MaskedAttention: out = softmax(tril(q k^T)) v, q/k/v = x @ W{q,k,v}
// B=8 T=2048 D=1024 H=64, fp32 in/out, no 1/sqrt(H) scaling.
//
// Precision plan: q,k projections and QK^T use hi/lo bf16 splitting
// (3-MFMA "bf16x3") so logits are ~fp32-accurate; V/P plain bf16.

typedef __bf16 bf16x8 __attribute__((ext_vector_type(8)));
typedef float f32x4 __attribute__((ext_vector_type(4)));

#define MFMA16(a, b, c) __builtin_amdgcn_mfma_f32_16x16x32_bf16((a), (b), (c), 0, 0, 0)
#define SB0() __builtin_amdgcn_sched_barrier(0)

static constexpr int BB = 8;
static constexpr int TT = 2048;
static constexpr int DD = 1024;
static constexpr int HH = 64;
static constexpr int NROW = BB * TT;       // 16384
// WC slab: [4 colgroups][2 K-halves][320 rows = k8l*5+frag][16 cols][8 bf16]
// frag: 0=q_hi 1=q_lo 2=k_hi 3=k_lo 4=v_hi. 80KB per (cg,half) slice.
static constexpr int WSLICE = 320 * 128;   // bf16 elems per (cg,half) = 80KB

// pack two floats to one u32 of 2 bf16 (lo, hi)
__device__ __forceinline__ unsigned pk2(float a, float b) {
  union { __bf16 h[2]; unsigned u; } r;
  r.h[0] = (__bf16)a;
  r.h[1] = (__bf16)b;
  return r.u;
}

// ---------------------------------------------------------------- W prep ---
// W [1024][64] fp32 -> WC slab (see above). Linear in (row,col) so proj can
// stage it to LDS with pure linear global_load_lds DMA.
__global__ __launch_bounds__(256) void wprep_kernel(
    const float* __restrict__ Wq, const float* __restrict__ Wk,
    const float* __restrict__ Wv, __bf16* __restrict__ WC) {
  int tid = blockIdx.x * 256 + threadIdx.x;
  if (tid >= 64 * 128) return;
  int col = tid >> 7;
  int k8 = tid & 127;
  const int g = col >> 4, c = col & 15;
  const int h2 = k8 >> 6, k8l = k8 & 63;
  bf16x8 q_h, q_l, k_h, k_l, v_h;
#pragma unroll
  for (int j = 0; j < 8; ++j) {
    const int k = k8 * 8 + j;
    float qv = Wq[k * 64 + col];
    float kv = Wk[k * 64 + col];
    float vv = Wv[k * 64 + col];
    __bf16 qhi = (__bf16)qv;
    __bf16 khi = (__bf16)kv;
    q_h[j] = qhi;
    q_l[j] = (__bf16)(qv - (float)qhi);
    k_h[j] = khi;
    k_l[j] = (__bf16)(kv - (float)khi);
    v_h[j] = (__bf16)vv;
  }
  __bf16* base = WC + (size_t)(g * 2 + h2) * WSLICE + (size_t)(k8l * 5) * 128 + c * 8;
  *(bf16x8*)(base) = q_h;            // row k8l*5+0
  *(bf16x8*)(base + 128) = q_l;      // row k8l*5+1
  *(bf16x8*)(base + 256) = k_h;      // row k8l*5+2
  *(bf16x8*)(base + 384) = k_l;      // row k8l*5+3
  *(bf16x8*)(base + 512) = v_h;      // row k8l*5+4
}

// ------------------------------------------------------------ projection ---
// Block = 512 threads (8 waves): 128 rows x ONE 16-col group, K in 2 halves.
// Per half: stage the 80KB W slice into LDS (10x global_load_lds dwordx4
// per thread, one barrier) -- all 8 waves share it. Main loop: per 32-K
// step, 2 x-loads (depth-4 rotation + SB0), 5 conflict-free ds_read_b128,
// 7 MFMA. Grid 512: rg=bid&127, cg=bid>>7 -> same-x blocks share an XCD L2.
__global__ __launch_bounds__(512, 4) void proj_kernel(
    const float* __restrict__ x, const __bf16* __restrict__ WC,
    __bf16* __restrict__ qh, __bf16* __restrict__ ql,
    __bf16* __restrict__ kh, __bf16* __restrict__ kl,
    __bf16* __restrict__ vt) {
  __shared__ __bf16 Wlds[WSLICE];  // 80 KB
  const int tid = threadIdx.x;
  const int w = tid >> 6, l = tid & 63;
  const int lr = l & 15, lg = l >> 4;
  const int rg = blockIdx.x & 127, cg = blockIdx.x >> 7;
  const int r0 = rg * 128 + w * 16;

  const float* xp = x + (size_t)(r0 + lr) * DD + lg * 8;
  // per-frag LDS base (bf16 elems): row (5*lg+m), chunk lr
  const int wb0 = (5 * lg + 0) * 128 + lr * 8;

  f32x4 aq = {0.f, 0.f, 0.f, 0.f};
  f32x4 ak = {0.f, 0.f, 0.f, 0.f};
  f32x4 av = {0.f, 0.f, 0.f, 0.f};
  float4 xa[4], xb[4];

#define LDX(J, OFF)                               \
  do {                                            \
    xa[J] = *(const float4*)(xp + (OFF));         \
    xb[J] = *(const float4*)(xp + (OFF) + 4);     \
  } while (0)

#define CMPW(J, S)                                                    \
  do {                                                                \
    const __bf16* fp = &Wlds[(S) * 2560 + wb0];                       \
    bf16x8 f0 = *(const bf16x8*)(fp);                                 \
    bf16x8 f1 = *(const bf16x8*)(fp + 128);                           \
    bf16x8 f2 = *(const bf16x8*)(fp + 256);                           \
    bf16x8 f3 = *(const bf16x8*)(fp + 384);                           \
    bf16x8 f4 = *(const bf16x8*)(fp + 512);                           \
    float xs[8] = {xa[J].x, xa[J].y, xa[J].z, xa[J].w,                \
                   xb[J].x, xb[J].y, xb[J].z, xb[J].w};               \
    bf16x8 ah, al;                                                    \
    _Pragma("unroll") for (int j = 0; j < 8; ++j) {                   \
      __bf16 hv = (__bf16)xs[j];                                      \
      ah[j] = hv;                                                     \
      al[j] = (__bf16)(xs[j] - (float)hv);                            \
    }                                                                 \
    aq = MFMA16(ah, f0, aq);                                          \
    aq = MFMA16(ah, f1, aq);                                          \
    aq = MFMA16(al, f0, aq);                                          \
    ak = MFMA16(ah, f2, ak);                                          \
    ak = MFMA16(ah, f3, ak);                                          \
    ak = MFMA16(al, f2, ak);                                          \
    av = MFMA16(ah, f4, av);                                          \
  } while (0)

#pragma unroll 1
  for (int h = 0; h < 2; ++h) {
    if (h) __syncthreads();  // all waves done reading half-0 W
    {
      const __bf16* wsrc = WC + (size_t)(cg * 2 + h) * WSLICE;
      const __bf16* gp = wsrc + (size_t)tid * 8;  // per-lane 16B cell
#pragma unroll
      for (int i2 = 0; i2 < 10; ++i2) {
        __builtin_amdgcn_global_load_lds(
            (const __attribute__((address_space(1))) unsigned int*)(gp + i2 * 4096),
            (__attribute__((address_space(3))) unsigned int*)
                ((char*)Wlds + w * 1024 + i2 * 8192),
            16, 0, 0);
      }
    }
    __syncthreads();  // compiler drains vmcnt before barrier: DMA complete

    const int xoff = h * 512;
    LDX(0, xoff); LDX(1, xoff + 32); LDX(2, xoff + 64); LDX(3, xoff + 96);
    SB0();
#pragma unroll
    for (int s = 0; s < 16; ++s) {
      CMPW(s & 3, s);
      if (s < 12) LDX(s & 3, xoff + (s + 4) * 32);
      SB0();
    }
  }
#undef LDX
#undef CMPW

#pragma unroll
  for (int i = 0; i < 4; ++i) {
    const int row = r0 + lg * 4 + i;  // C-layout: row=(lane>>4)*4+reg
    const int col = cg * 16 + lr;     //           col=lane&15
    const size_t oq = (size_t)row * 64 + col;
    float qv = aq[i];
    __bf16 qhi = (__bf16)qv;
    qh[oq] = qhi;
    ql[oq] = (__bf16)(qv - (float)qhi);
    float kv = ak[i];
    __bf16 khi = (__bf16)kv;
    kh[oq] = khi;
    kl[oq] = (__bf16)(kv - (float)khi);
    const int bb = row >> 11, tt = row & 2047;
    vt[((size_t)bb * 64 + col) * 2048 + tt] = (__bf16)av[i];
  }
}

// -------------------------------------------------------------- attention ---
// Split-K flash, 4-wave blocks, K STAGED THROUGH LDS. R8/R10/R11 ledger:
// three register-staged schedules all ~63-70us because the allocator
// (56-64 VGPR) cannot hold K(32)+V(16)+Q(16)+acc(16) -> loads serialize
// in 2-3 latency windows/iter (proj had the identical disease, fixed 3x
// by global_load_lds in R5). Now: 128-key supersteps; all 256 threads DMA
// kh+kl (32KB) to LDS with XOR-pre-swizzled source (rule #21: linear dest,
// swizzled src + same XOR on ds_read -> conflict-free b128); ONE vmcnt
// drain per superstep instead of ~12 scattered waits; V (4 loads, 16 reg)
// issued before the drain so its latency hides under it. K-LDS buffer is
// aliased with the post-loop merge buffer: LDS 33.5KB -> 4 blocks/CU,
// all 1024 blocks resident, b=bid&7 XCD affinity preserved.
__global__ __launch_bounds__(256, 4) void attn_kernel(
    const __bf16* __restrict__ qh, const __bf16* __restrict__ ql,
    const __bf16* __restrict__ kh, const __bf16* __restrict__ kl,
    const __bf16* __restrict__ vt, float* __restrict__ out) {
  __shared__ char BUF[32768] __attribute__((aligned(16)));  // K stage / merge
  __shared__ float Sm[4][16];       // per-wave row maxes
  __shared__ float Sl[4][16];       // per-wave row sums
  __shared__ float Dinv[16];        // 1/denom per row
  const int w = threadIdx.x >> 6, l = threadIdx.x & 63;
  const int lr = l & 15, lg = l >> 4;
  const int b = blockIdx.x & 7;            // XCD affinity: batch -> XCD
  const int qt = 127 - (blockIdx.x >> 3);  // heavy tiles first
  const int q0 = qt * 16;
  const float NEG = -__builtin_inff();

  // Q fragments (B-operand of the swapped QK^T)
  const size_t qb = ((size_t)b * TT + q0 + lr) * 64 + lg * 8;
  const bf16x8 fqh0 = *(const bf16x8*)(qh + qb);
  const bf16x8 fqh1 = *(const bf16x8*)(qh + qb + 32);
  const bf16x8 fql0 = *(const bf16x8*)(ql + qb);
  const bf16x8 fql1 = *(const bf16x8*)(ql + qb + 32);

  f32x4 o0 = {0.f, 0.f, 0.f, 0.f}, o1 = o0, o2 = o0, o3 = o0;
  float m_s = NEG;   // running max for q-row (q0+lr), shared by 4 lg-lanes
  float su_s = 0.f;  // partial denom for q-row (this lane's keys only)
  const int nkt = (q0 + 47) >> 5;    // ceil((q0+16)/32)
  const int nsup = (nkt + 3) >> 2;   // 128-key supersteps

  bf16x8 v0, v1, v2, v3;
  f32x4 sa, sb;

  // LDS element offset for logical (row r, colgroup c) with XOR swizzle.
  // kh rows at bf16 index 0.., kl at +8192 (byte 16384).
#define KOFF(R, C) ((R) * 64 + ((((C) ^ ((R)&7))) * 8))

  // Stage kh+kl for keys [sup*128, +128) into BUF. Dest is linear
  // (slot = w*1024 + i*4096 + lane*16 -> row w*8+i*32+(l>>3), cg l&7);
  // source colgroup pre-swizzled: (l&7)^(l>>3) since row&7 == l>>3.
#define STAGE(SUP)                                                         \
  do {                                                                     \
    const size_t kbase_ = ((size_t)b * TT + (size_t)(SUP) * 128) * 64;     \
    const size_t rowco_ = (size_t)(w * 8 + (l >> 3)) * 64 +                \
                          (size_t)(((l & 7) ^ (l >> 3)) * 8);              \
    const __bf16* srck_ = kh + kbase_ + rowco_;                            \
    const __bf16* srcl_ = kl + kbase_ + rowco_;                            \
    _Pragma("unroll") for (int i_ = 0; i_ < 4; ++i_) {                     \
      __builtin_amdgcn_global_load_lds(                                    \
          (const __attribute__((address_space(1))) unsigned int*)(srck_ + i_ * 2048), \
          (__attribute__((address_space(3))) unsigned int*)(BUF + w * 1024 + i_ * 4096), \
          16, 0, 0);                                                       \
    }                                                                      \
    _Pragma("unroll") for (int i_ = 0; i_ < 4; ++i_) {                     \
      __builtin_amdgcn_global_load_lds(                                    \
          (const __attribute__((address_space(1))) unsigned int*)(srcl_ + i_ * 2048), \
          (__attribute__((address_space(3))) unsigned int*)(BUF + 16384 + w * 1024 + i_ * 4096), \
          16, 0, 0);                                                       \
    }                                                                      \
  } while (0)

#define LDV(KT)                                                        \
  do {                                                                 \
    const size_t vb_ =                                                 \
        ((size_t)b * 64 + lr) * 2048 + (KT) * 32 + lg * 8;             \
    v0 = *(const bf16x8*)(vt + vb_);                                   \
    v1 = *(const bf16x8*)(vt + vb_ + (size_t)16 * 2048);               \
    v2 = *(const bf16x8*)(vt + vb_ + (size_t)32 * 2048);               \
    v3 = *(const bf16x8*)(vt + vb_ + (size_t)48 * 2048);               \
  } while (0)

  // QK^T from LDS K (wave w's 32-key tile = buffer rows w*32..w*32+31).
#define QKM(KT)                                                        \
  do {                                                                 \
    const int j0_ = (KT) * 32;                                         \
    const int rA_ = w * 32 + lr, rB_ = rA_ + 16;                       \
    const __bf16* Kb_ = (const __bf16*)BUF;                            \
    const bf16x8 fk0 = *(const bf16x8*)(Kb_ + KOFF(rA_, lg));          \
    const bf16x8 fk1 = *(const bf16x8*)(Kb_ + KOFF(rA_, 4 + lg));      \
    const bf16x8 fl0 = *(const bf16x8*)(Kb_ + 8192 + KOFF(rA_, lg));   \
    const bf16x8 fl1 = *(const bf16x8*)(Kb_ + 8192 + KOFF(rA_, 4 + lg)); \
    const bf16x8 gk0 = *(const bf16x8*)(Kb_ + KOFF(rB_, lg));          \
    const bf16x8 gk1 = *(const bf16x8*)(Kb_ + KOFF(rB_, 4 + lg));      \
    const bf16x8 gl0 = *(const bf16x8*)(Kb_ + 8192 + KOFF(rB_, lg));   \
    const bf16x8 gl1 = *(const bf16x8*)(Kb_ + 8192 + KOFF(rB_, 4 + lg)); \
    const f32x4 z_ = {0.f, 0.f, 0.f, 0.f};                             \
    {                                                                  \
      f32x4 c0_ = MFMA16(fk1, fqh1, MFMA16(fk0, fqh0, z_));            \
      f32x4 c1_ = MFMA16(fk1, fql1, MFMA16(fk0, fql0, z_));            \
      f32x4 c2_ = MFMA16(fl1, fqh1, MFMA16(fl0, fqh0, z_));            \
      sa = c0_ + c1_ + c2_;                                            \
    }                                                                  \
    sb = (f32x4){NEG, NEG, NEG, NEG};                                  \
    if ((j0_ + 16) <= (q0 + 15)) {                                     \
      f32x4 c0_ = MFMA16(gk1, fqh1, MFMA16(gk0, fqh0, z_));            \
      f32x4 c1_ = MFMA16(gk1, fql1, MFMA16(gk0, fql0, z_));            \
      f32x4 c2_ = MFMA16(gl1, fqh1, MFMA16(gl0, fqh0, z_));            \
      sb = c0_ + c1_ + c2_;                                            \
    }                                                                  \
    _Pragma("unroll") for (int i = 0; i < 4; ++i) {                    \
      if (j0_ + lg * 4 + i > q0 + lr) sa[i] = NEG;                     \
      if (j0_ + 16 + lg * 4 + i > q0 + lr) sb[i] = NEG;                \
    }                                                                  \
  } while (0)

#define SPV()                                                          \
  do {                                                                 \
    float t_ = fmaxf(fmaxf(fmaxf(sa[0], sa[1]), fmaxf(sa[2], sa[3])),  \
                     fmaxf(fmaxf(sb[0], sb[1]), fmaxf(sb[2], sb[3]))); \
    t_ = fmaxf(t_, __shfl_xor(t_, 16, 64));                            \
    t_ = fmaxf(t_, __shfl_xor(t_, 32, 64));                            \
    const float mn_ = fmaxf(m_s, t_);                                  \
    const float sc_ = __expf(m_s - mn_);                               \
    m_s = mn_;                                                         \
    const float pa0_ = __expf(sa[0] - mn_), pa1_ = __expf(sa[1] - mn_);\
    const float pa2_ = __expf(sa[2] - mn_), pa3_ = __expf(sa[3] - mn_);\
    const float pb0_ = __expf(sb[0] - mn_), pb1_ = __expf(sb[1] - mn_);\
    const float pb2_ = __expf(sb[2] - mn_), pb3_ = __expf(sb[3] - mn_);\
    su_s = su_s * sc_ + ((pa0_ + pa1_) + (pa2_ + pa3_)) +              \
           ((pb0_ + pb1_) + (pb2_ + pb3_));                            \
    _Pragma("unroll") for (int i = 0; i < 4; ++i) {                    \
      const float scr_ = __shfl(sc_, lg * 4 + i, 64);                  \
      o0[i] *= scr_; o1[i] *= scr_; o2[i] *= scr_; o3[i] *= scr_;      \
    }                                                                  \
    const unsigned x0_ = pk2(pa0_, pa1_), x1_ = pk2(pa2_, pa3_);       \
    const unsigned y0_ = pk2(pb0_, pb1_), y1_ = pk2(pb2_, pb3_);       \
    const bool e_ = (lg & 1) != 0;                                     \
    const unsigned s0_ = e_ ? x0_ : y0_, s1_ = e_ ? x1_ : y1_;         \
    const unsigned r0_ = __shfl_xor(s0_, 16, 64);                      \
    const unsigned r1_ = __shfl_xor(s1_, 16, 64);                      \
    unsigned z0_ = e_ ? r0_ : x0_;                                     \
    unsigned z1_ = e_ ? r1_ : x1_;                                     \
    unsigned z2_ = e_ ? y0_ : r0_;                                     \
    unsigned z3_ = e_ ? y1_ : r1_;                                     \
    const unsigned u0_ = __shfl_xor(z0_, 48, 64);                      \
    const unsigned u1_ = __shfl_xor(z1_, 48, 64);                      \
    const unsigned u2_ = __shfl_xor(z2_, 48, 64);                      \
    const unsigned u3_ = __shfl_xor(z3_, 48, 64);                      \
    const bool sw_ = (lg == 1) || (lg == 2);                           \
    z0_ = sw_ ? u0_ : z0_; z1_ = sw_ ? u1_ : z1_;                      \
    z2_ = sw_ ? u2_ : z2_; z3_ = sw_ ? u3_ : z3_;                      \
    union { unsigned u[4]; bf16x8 v; } pfu_;                           \
    pfu_.u[0] = z0_; pfu_.u[1] = z1_;                                  \
    pfu_.u[2] = z2_; pfu_.u[3] = z3_;                                  \
    const bf16x8 pf_ = pfu_.v;                                         \
    o0 = MFMA16(pf_, v0, o0);                                          \
    o1 = MFMA16(pf_, v1, o1);                                          \
    o2 = MFMA16(pf_, v2, o2);                                          \
    o3 = MFMA16(pf_, v3, o3);                                          \
  } while (0)

#pragma unroll 1
  for (int sup = 0; sup < nsup; ++sup) {
    if (sup) __syncthreads();        // waves done reading previous K tiles
    STAGE(sup);                      // DMA kh+kl (32KB) -> BUF
    const int kt = sup * 4 + w;      // this wave's tile in the superstep
    const bool act = kt < nkt;       // wave-uniform
    if (act) LDV(kt);                // V in regs; hidden under the drain
    __syncthreads();                 // vmcnt(0) drain: DMA + V complete
    if (act) {
      QKM(kt);                       // K frags from LDS (swizzled ds_read)
      SPV();
    }
  }
#undef KOFF
#undef STAGE
#undef LDV
#undef QKM
#undef SPV

  // per-output-row final running max; full row denom (sum over 4 lg-lanes)
  float m_or[4];
#pragma unroll
  for (int i = 0; i < 4; ++i) m_or[i] = __shfl(m_s, lg * 4 + i, 64);
  float su_row = su_s;
  su_row += __shfl_xor(su_row, 16, 64);
  su_row += __shfl_xor(su_row, 32, 64);

  // ------- LSE merge of the 4 per-wave partials (OB aliases BUF) -------
  float (*OB)[16][68] = (float (*)[16][68])BUF;  // 4*16*68*4 = 17408 B
  if (l < 16) {  // lg==0 lanes cover lr=0..15
    Sm[w][l] = m_s;
    Sl[w][l] = su_row;
  }
  __syncthreads();  // also fences last K reads before BUF reuse
#pragma unroll
  for (int i = 0; i < 4; ++i) {
    const int row = lg * 4 + i;
    float M = fmaxf(fmaxf(Sm[0][row], Sm[1][row]),
                    fmaxf(Sm[2][row], Sm[3][row]));
    const float sc = __expf(m_or[i] - M);  // 0 if this wave was idle
    OB[w][row][lr] = o0[i] * sc;
    OB[w][row][16 + lr] = o1[i] * sc;
    OB[w][row][32 + lr] = o2[i] * sc;
    OB[w][row][48 + lr] = o3[i] * sc;
    if (w == 0 && lr == 0) {
      float denom = 0.f;
#pragma unroll
      for (int w2 = 0; w2 < 4; ++w2)
        denom += Sl[w2][row] * __expf(Sm[w2][row] - M);
      Dinv[row] = 1.0f / denom;
    }
  }
  __syncthreads();
  const int t2 = threadIdx.x;
#pragma unroll
  for (int k2 = 0; k2 < 4; ++k2) {
    const int e2 = t2 + 256 * k2;
    const int row = e2 >> 6, col = e2 & 63;
    const float s = OB[0][row][col] + OB[1][row][col] + OB[2][row][col] +
                    OB[3][row][col];
    out[((size_t)b * TT + q0 + row) * 64 + col] = s * Dinv[row];
  }
}

// ------------------------------------------------------------------ launch ---
extern "C" void kernel_launch(void* const* d_in, const int* in_sizes, int n_in,
                              void* d_out, int out_size, void* d_ws,
                              size_t ws_size, hipStream_t stream) {
  const float* x = (const float*)d_in[0];
  const float* Wq = (const float*)d_in[1];
  const float* Wk = (const float*)d_in[2];
  const float* Wv = (const float*)d_in[3];
  float* out = (float*)d_out;
  char* ws = (char*)d_ws;

  size_t off = 0;
  __bf16* WC = (__bf16*)(ws + off); off += (size_t)8 * WSLICE * 2;  // 655KB
  __bf16* qh = (__bf16*)(ws + off); off += (size_t)NROW * 64 * 2;
  __bf16* ql = (__bf16*)(ws + off); off += (size_t)NROW * 64 * 2;
  __bf16* kh = (__bf16*)(ws + off); off += (size_t)NROW * 64 * 2;
  __bf16* kl = (__bf16*)(ws + off); off += (size_t)NROW * 64 * 2;
  __bf16* vt = (__bf16*)(ws + off); off += (size_t)NROW * 64 * 2;  // ~11.1 MB

  wprep_kernel<<<dim3(32), dim3(256), 0, stream>>>(Wq, Wk, Wv, WC);
  proj_kernel<<<dim3(512), dim3(512), 0, stream>>>(
      x, WC, qh, ql, kh, kl, vt);
  attn_kernel<<<dim3(1024), dim3(256), 0, stream>>>(
      qh, ql, kh, kl, vt, out);
}